// Round 1
// baseline (364.244 us; speedup 1.0000x reference)
//
#include <hip/hip_runtime.h>
#include <stdint.h>

#define DD 2048
#define SS 2048
#define NB 2
#define NH 16
#define HDIM 128
#define MM (NB*SS)   // 4096 rows

typedef __attribute__((ext_vector_type(8))) short bf16x8;
typedef __attribute__((ext_vector_type(4))) float f32x4;

__device__ __forceinline__ ushort f2bf(float f) {
  union { float f; uint32_t u; } v; v.f = f;
  uint32_t u = v.u;
  return (ushort)((u + 0x7fffu + ((u >> 16) & 1u)) >> 16);
}

__device__ __forceinline__ void gld_lds16(const ushort* g, ushort* l) {
  __builtin_amdgcn_global_load_lds(
      (const __attribute__((address_space(1))) void*)g,
      (__attribute__((address_space(3))) void*)l, 16, 0, 0);
}

// ---------------- fp32 -> bf16 conversion of x and the 4 weights -------------
__global__ __launch_bounds__(256) void cvt_all(
    const float* __restrict__ x, const float* __restrict__ wq,
    const float* __restrict__ wk, const float* __restrict__ wv,
    const float* __restrict__ wo, ushort* __restrict__ dst)
{
  int i8 = blockIdx.x * 256 + threadIdx.x;   // one 8-float chunk per thread
  const int X8 = MM * DD / 8;                // 1,048,576
  const int W8 = DD * DD / 8;                // 524,288
  const float* src; int off;
  if (i8 < X8)            { src = x;  off = i8; }
  else if (i8 < X8 +   W8){ src = wq; off = i8 - X8; }
  else if (i8 < X8 + 2*W8){ src = wk; off = i8 - (X8 +   W8); }
  else if (i8 < X8 + 3*W8){ src = wv; off = i8 - (X8 + 2*W8); }
  else                    { src = wo; off = i8 - (X8 + 3*W8); }
  const float4* p = (const float4*)src;
  float4 a = p[(long)off*2], b = p[(long)off*2 + 1];
  bf16x8 o;
  o[0]=(short)f2bf(a.x); o[1]=(short)f2bf(a.y); o[2]=(short)f2bf(a.z); o[3]=(short)f2bf(a.w);
  o[4]=(short)f2bf(b.x); o[5]=(short)f2bf(b.y); o[6]=(short)f2bf(b.z); o[7]=(short)f2bf(b.w);
  *(bf16x8*)(dst + (long)i8*8) = o;
}

// ---------------- m97-structure GEMM: C = A(MxK) * Bt(NxK)^T -----------------
// 128x128 tile, BK=32, 4 waves (2x2), 16x16x32 bf16 MFMA, global_load_lds w=16
template<int OBF>
__global__ __launch_bounds__(256) void gemm_bt(
    const ushort* __restrict__ A, const ushort* __restrict__ Bt,
    void* __restrict__ Cv, int Mm, int Nn, int Kk, float scale)
{
  __shared__ ushort As[4096];
  __shared__ ushort Bs[4096];
  const int nbn = Nn >> 7;
  const int nwg = (Mm >> 7) * nbn;           // divisible by 8 here (512)
  int bid = blockIdx.x;
  int swz = (bid & 7) * (nwg >> 3) + (bid >> 3);   // XCD-aware, bijective
  int bm = swz / nbn, bn = swz % nbn;
  const int t = threadIdx.x;
  const int lane = t & 63;
  const int wr = t >> 7, wc = (t >> 6) & 1;

  f32x4 acc[4][4] = {};

  const ushort* ga0 = A  + (long)(bm*128 + (t>>2)) * Kk + (t&3)*8;
  const ushort* ga1 = ga0 + (long)64 * Kk;
  const ushort* gb0 = Bt + (long)(bn*128 + (t>>2)) * Kk + (t&3)*8;
  const ushort* gb1 = gb0 + (long)64 * Kk;
  ushort* la0 = As + t*8;  ushort* la1 = As + 2048 + t*8;
  ushort* lb0 = Bs + t*8;  ushort* lb1 = Bs + 2048 + t*8;

  const ushort* pa = As + (wr*64 + (lane & 15)) * 32 + (lane >> 4) * 8;
  const ushort* pb = Bs + (wc*64 + (lane & 15)) * 32 + (lane >> 4) * 8;

  for (int kt = 0; kt < Kk; kt += 32) {
    gld_lds16(ga0, la0); gld_lds16(ga1, la1);
    gld_lds16(gb0, lb0); gld_lds16(gb1, lb1);
    ga0 += 32; ga1 += 32; gb0 += 32; gb1 += 32;
    __syncthreads();                           // vmcnt(0) drain -> LDS ready
    bf16x8 af[4], bfr[4];
#pragma unroll
    for (int m = 0; m < 4; ++m) af[m]  = *(const bf16x8*)(pa + m*16*32);
#pragma unroll
    for (int n = 0; n < 4; ++n) bfr[n] = *(const bf16x8*)(pb + n*16*32);
#pragma unroll
    for (int m = 0; m < 4; ++m)
#pragma unroll
      for (int n = 0; n < 4; ++n)
        acc[m][n] = __builtin_amdgcn_mfma_f32_16x16x32_bf16(af[m], bfr[n], acc[m][n], 0, 0, 0);
    __syncthreads();                           // readers done before restage
  }

  int cr = bm*128 + wr*64 + (lane >> 4) * 4;   // C/D: row=(l>>4)*4+reg
  int cc = bn*128 + wc*64 + (lane & 15);       //      col=l&15
#pragma unroll
  for (int m = 0; m < 4; ++m)
#pragma unroll
    for (int n = 0; n < 4; ++n)
#pragma unroll
      for (int j = 0; j < 4; ++j) {
        float v = acc[m][n][j] * scale;
        long idx = (long)(cr + m*16 + j) * Nn + (cc + n*16);
        if (OBF) ((ushort*)Cv)[idx] = f2bf(v);
        else     ((float*)Cv)[idx]  = v;
      }
}

// ---------------- causal flash attention ------------------------------------
// 4 waves x 32 q-rows = 128-row Q tile; KV tiles of 64; K in LDS XOR-swizzled;
// V reg-staged transposed (Vt[d][k], stride 72); P via per-wave LDS.
__global__ __launch_bounds__(256) void attn_fwd(
    const ushort* __restrict__ Qb, const ushort* __restrict__ Kb,
    const ushort* __restrict__ Vb, ushort* __restrict__ Ob)
{
  __shared__ ushort Ks[64*128];     // swizzled row-major [k][d]
  __shared__ ushort Vt[128*72];     // transposed [d][k], padded stride 72
  __shared__ ushort Ps[4*32*72];    // per-wave P [32][64], padded stride 72

  int bid = blockIdx.x;
  int qt = 15 - (bid >> 5);         // LPT: heaviest q-tiles dispatch first
  int bh = bid & 31;
  int b = bh >> 4, h = bh & 15;
  const int t = threadIdx.x;
  const int lane = t & 63;
  const int wq = t >> 6;
  const int lr = lane & 15, lg = lane >> 4;

  const int qbase = qt * 128;
  const long rowQ = (long)(b * SS + qbase + wq * 32);

  bf16x8 qf[2][4];                  // Q in registers (pre-scaled by 1/sqrt(hd))
#pragma unroll
  for (int i = 0; i < 2; ++i)
#pragma unroll
    for (int c = 0; c < 4; ++c)
      qf[i][c] = *(const bf16x8*)(Qb + (rowQ + i*16 + lr) * DD + h*HDIM + c*32 + lg*8);

  f32x4 accO[2][8] = {};
  float mrow[2][4], lrow[2][4];
#pragma unroll
  for (int i = 0; i < 2; ++i)
#pragma unroll
    for (int j = 0; j < 4; ++j) { mrow[i][j] = -1e30f; lrow[i][j] = 0.f; }

  const ushort* Kg = Kb + (long)(b * SS) * DD + h * HDIM;
  const ushort* Vg = Vb + (long)(b * SS) * DD + h * HDIM;

  const int ktmax = 2*qt + 1;
  const int qmaxw = qbase + wq*32 + 31;
  const int skr = t >> 4;           // K-stage row base (0..15)
  const int skd = (t & 15) * 8;     // K-stage d offset (coalesced)
  const int svr = t & 15;           // V-stage row base
  const int svd = (t >> 4) * 8;     // V-stage d offset

  ushort* myP = Ps + wq * 2304;

  for (int kt = 0; kt <= ktmax; ++kt) {
    const int k0 = kt * 64;
    bf16x8 kreg[4], vreg[4];
#pragma unroll
    for (int c = 0; c < 4; ++c) {
      kreg[c] = *(const bf16x8*)(Kg + (long)(k0 + skr + 16*c) * DD + skd);
      vreg[c] = *(const bf16x8*)(Vg + (long)(k0 + svr + 16*c) * DD + svd);
    }
#pragma unroll
    for (int c = 0; c < 4; ++c) {   // K: XOR-swizzled b128 writes (G4 fix)
      int r = skr + 16*c;
      int byteoff = (r*256 + (t & 15)*16) ^ ((r & 7) << 4);
      *(bf16x8*)((char*)Ks + byteoff) = kreg[c];
    }
#pragma unroll
    for (int c = 0; c < 4; ++c)     // V: scatter-transpose into Vt[d][k]
#pragma unroll
      for (int jj = 0; jj < 8; ++jj)
        Vt[(svd + jj)*72 + svr + 16*c] = (ushort)vreg[c][jj];
    __syncthreads();

    if (k0 <= qmaxw) {              // wave-uniform causal skip
      f32x4 sc[2][4] = {};
#pragma unroll
      for (int n = 0; n < 4; ++n) { // S = Q * K^T
        int r = n*16 + lr;
        int swz = (r & 7) << 4;
#pragma unroll
        for (int c = 0; c < 4; ++c) {
          bf16x8 kf = *(const bf16x8*)((const char*)Ks + ((r*256 + c*64 + lg*16) ^ swz));
          sc[0][n] = __builtin_amdgcn_mfma_f32_16x16x32_bf16(qf[0][c], kf, sc[0][n], 0,0,0);
          sc[1][n] = __builtin_amdgcn_mfma_f32_16x16x32_bf16(qf[1][c], kf, sc[1][n], 0,0,0);
        }
      }
      if (kt >= 2*qt) {             // diagonal tiles: causal mask
#pragma unroll
        for (int i = 0; i < 2; ++i)
#pragma unroll
          for (int n = 0; n < 4; ++n)
#pragma unroll
            for (int j = 0; j < 4; ++j) {
              int kpos = k0 + n*16 + lr;
              int qpos = qbase + wq*32 + i*16 + lg*4 + j;
              if (kpos > qpos) sc[i][n][j] = -1e30f;
            }
      }
      float al[2][4];
#pragma unroll
      for (int i = 0; i < 2; ++i)   // online softmax (rows live in 16 lanes)
#pragma unroll
        for (int j = 0; j < 4; ++j) {
          float tm = fmaxf(fmaxf(sc[i][0][j], sc[i][1][j]), fmaxf(sc[i][2][j], sc[i][3][j]));
#pragma unroll
          for (int off = 1; off < 16; off <<= 1) tm = fmaxf(tm, __shfl_xor(tm, off));
          float mn = fmaxf(mrow[i][j], tm);
          float a = __expf(mrow[i][j] - mn);
          mrow[i][j] = mn;
          float ts = 0.f;
#pragma unroll
          for (int n = 0; n < 4; ++n) {
            float p = __expf(sc[i][n][j] - mn);
            sc[i][n][j] = p; ts += p;
          }
#pragma unroll
          for (int off = 1; off < 16; off <<= 1) ts += __shfl_xor(ts, off);
          lrow[i][j] = lrow[i][j] * a + ts;
          al[i][j] = a;
        }
#pragma unroll
      for (int i = 0; i < 2; ++i)
#pragma unroll
        for (int dg = 0; dg < 8; ++dg) {
          f32x4 v = accO[i][dg];
          v[0] *= al[i][0]; v[1] *= al[i][1]; v[2] *= al[i][2]; v[3] *= al[i][3];
          accO[i][dg] = v;
        }
#pragma unroll
      for (int i = 0; i < 2; ++i)   // P -> per-wave LDS (D-layout -> A-layout)
#pragma unroll
        for (int n = 0; n < 4; ++n)
#pragma unroll
          for (int j = 0; j < 4; ++j)
            myP[(i*16 + lg*4 + j)*72 + n*16 + lr] = f2bf(sc[i][n][j]);
      bf16x8 pa[2][2];
#pragma unroll
      for (int i = 0; i < 2; ++i)
#pragma unroll
        for (int kc = 0; kc < 2; ++kc)
          pa[i][kc] = *(const bf16x8*)(myP + (i*16 + lr)*72 + kc*32 + lg*8);
#pragma unroll
      for (int dg = 0; dg < 8; ++dg) {  // O += P * V
        bf16x8 v0 = *(const bf16x8*)(Vt + (dg*16 + lr)*72 + lg*8);
        bf16x8 v1 = *(const bf16x8*)(Vt + (dg*16 + lr)*72 + 32 + lg*8);
        accO[0][dg] = __builtin_amdgcn_mfma_f32_16x16x32_bf16(pa[0][0], v0, accO[0][dg], 0,0,0);
        accO[0][dg] = __builtin_amdgcn_mfma_f32_16x16x32_bf16(pa[0][1], v1, accO[0][dg], 0,0,0);
        accO[1][dg] = __builtin_amdgcn_mfma_f32_16x16x32_bf16(pa[1][0], v0, accO[1][dg], 0,0,0);
        accO[1][dg] = __builtin_amdgcn_mfma_f32_16x16x32_bf16(pa[1][1], v1, accO[1][dg], 0,0,0);
      }
    }
    __syncthreads();
  }

  ushort* Og = Ob + rowQ * DD + h * HDIM;
#pragma unroll
  for (int i = 0; i < 2; ++i)
#pragma unroll
    for (int dg = 0; dg < 8; ++dg)
#pragma unroll
      for (int j = 0; j < 4; ++j) {
        float o = accO[i][dg][j] / lrow[i][j];
        Og[(long)(i*16 + lg*4 + j) * DD + dg*16 + lr] = f2bf(o);
      }
}

// ---------------- launch ----------------------------------------------------
extern "C" void kernel_launch(void* const* d_in, const int* in_sizes, int n_in,
                              void* d_out, int out_size, void* d_ws, size_t ws_size,
                              hipStream_t stream) {
  const float* x  = (const float*)d_in[0];
  const float* Wq = (const float*)d_in[1];
  const float* Wk = (const float*)d_in[2];
  const float* Wv = (const float*)d_in[3];
  const float* Wo = (const float*)d_in[4];

  ushort* ws  = (ushort*)d_ws;
  ushort* xb  = ws;                         // x bf16; later reused as attn-out
  ushort* wqb = ws  + (long)MM*DD;
  ushort* wkb = wqb + (long)DD*DD;
  ushort* wvb = wkb + (long)DD*DD;
  ushort* wob = wvb + (long)DD*DD;
  ushort* Qb  = wob + (long)DD*DD;
  ushort* Kb  = Qb  + (long)MM*DD;
  ushort* Vb  = Kb  + (long)MM*DD;          // total ~100.7 MB of ws

  const int CVT_BLOCKS = (MM*DD + 4*DD*DD) / 8 / 256;   // 12288
  cvt_all<<<CVT_BLOCKS, 256, 0, stream>>>(x, Wq, Wk, Wv, Wo, ws);

  const float qscale = 0.08838834764831845f;  // 1/sqrt(128), folded into Q
  gemm_bt<1><<<512, 256, 0, stream>>>(xb, wqb, Qb, MM, DD, DD, qscale);
  gemm_bt<1><<<512, 256, 0, stream>>>(xb, wkb, Kb, MM, DD, DD, 1.0f);
  gemm_bt<1><<<512, 256, 0, stream>>>(xb, wvb, Vb, MM, DD, DD, 1.0f);

  attn_fwd<<<512, 256, 0, stream>>>(Qb, Kb, Vb, xb);    // attn out -> xb

  gemm_bt<0><<<512, 256, 0, stream>>>(xb, wob, d_out, MM, DD, DD, 1.0f);
}

// Round 4
// 319.947 us; speedup vs baseline: 1.1385x; 1.1385x over previous
//
#include <hip/hip_runtime.h>
#include <stdint.h>

#define DD 2048
#define SS 2048
#define NB 2
#define NH 16
#define HDIM 128
#define MM (NB*SS)   // 4096 rows

typedef __attribute__((ext_vector_type(8))) short bf16x8;
typedef __attribute__((ext_vector_type(4))) float f32x4;
typedef __attribute__((ext_vector_type(4))) ushort u16x4;

__device__ __forceinline__ float fast_exp2(float x) {
  return __builtin_amdgcn_exp2f(x);   // v_exp_f32 (2^x natively)
}

__device__ __forceinline__ ushort f2bf(float f) {
  union { float f; uint32_t u; } v; v.f = f;
  uint32_t u = v.u;
  return (ushort)((u + 0x7fffu + ((u >> 16) & 1u)) >> 16);
}

__device__ __forceinline__ void gld_lds16(const ushort* g, ushort* l) {
  __builtin_amdgcn_global_load_lds(
      (const __attribute__((address_space(1))) void*)g,
      (__attribute__((address_space(3))) void*)l, 16, 0, 0);
}

// ---------------- fp32 -> bf16 conversion of x and the 4 weights -------------
__global__ __launch_bounds__(256) void cvt_all(
    const float* __restrict__ x, const float* __restrict__ wq,
    const float* __restrict__ wk, const float* __restrict__ wv,
    const float* __restrict__ wo, ushort* __restrict__ dst)
{
  int i8 = blockIdx.x * 256 + threadIdx.x;   // one 8-float chunk per thread
  const int X8 = MM * DD / 8;                // 1,048,576
  const int W8 = DD * DD / 8;                // 524,288
  const float* src; int off;
  if (i8 < X8)            { src = x;  off = i8; }
  else if (i8 < X8 +   W8){ src = wq; off = i8 - X8; }
  else if (i8 < X8 + 2*W8){ src = wk; off = i8 - (X8 +   W8); }
  else if (i8 < X8 + 3*W8){ src = wv; off = i8 - (X8 + 2*W8); }
  else                    { src = wo; off = i8 - (X8 + 3*W8); }
  const float4* p = (const float4*)src;
  float4 a = p[(long)off*2], b = p[(long)off*2 + 1];
  bf16x8 o;
  o[0]=(short)f2bf(a.x); o[1]=(short)f2bf(a.y); o[2]=(short)f2bf(a.z); o[3]=(short)f2bf(a.w);
  o[4]=(short)f2bf(b.x); o[5]=(short)f2bf(b.y); o[6]=(short)f2bf(b.z); o[7]=(short)f2bf(b.w);
  *(bf16x8*)(dst + (long)i8*8) = o;
}

// ---------------- fused QKV GEMM: [Q|K|V] = x * [Wq;Wk;Wv]^T -----------------
// m97 structure; V region written TRANSPOSED to Vt[(b*16+h)*128+d][s] so the
// attention kernel never transposes V. Q region pre-scaled by 1/sqrt(hd)*log2e.
__global__ __launch_bounds__(256) void gemm_qkv(
    const ushort* __restrict__ A, const ushort* __restrict__ Bt,
    ushort* __restrict__ Qo, ushort* __restrict__ Ko, ushort* __restrict__ Vt)
{
  __shared__ ushort As[4096];
  __shared__ ushort Bs[4096];
  const int nbn = 48;                         // 6144/128
  const int nwg = 32 * 48;                    // 1536, %8==0 -> bijective swz
  int bid = blockIdx.x;
  int swz = (bid & 7) * (nwg >> 3) + (bid >> 3);
  int bm = swz / nbn, bn = swz % nbn;
  const int t = threadIdx.x;
  const int lane = t & 63;
  const int wr = t >> 7, wc = (t >> 6) & 1;

  f32x4 acc[4][4] = {};

  const ushort* ga0 = A  + (long)(bm*128 + (t>>2)) * DD + (t&3)*8;
  const ushort* ga1 = ga0 + (long)64 * DD;
  const ushort* gb0 = Bt + (long)(bn*128 + (t>>2)) * DD + (t&3)*8;
  const ushort* gb1 = gb0 + (long)64 * DD;
  ushort* la0 = As + t*8;  ushort* la1 = As + 2048 + t*8;
  ushort* lb0 = Bs + t*8;  ushort* lb1 = Bs + 2048 + t*8;

  const ushort* pa = As + (wr*64 + (lane & 15)) * 32 + (lane >> 4) * 8;
  const ushort* pb = Bs + (wc*64 + (lane & 15)) * 32 + (lane >> 4) * 8;

  for (int kt = 0; kt < DD; kt += 32) {
    gld_lds16(ga0, la0); gld_lds16(ga1, la1);
    gld_lds16(gb0, lb0); gld_lds16(gb1, lb1);
    ga0 += 32; ga1 += 32; gb0 += 32; gb1 += 32;
    __syncthreads();
    bf16x8 af[4], bfr[4];
#pragma unroll
    for (int m = 0; m < 4; ++m) af[m]  = *(const bf16x8*)(pa + m*16*32);
#pragma unroll
    for (int n = 0; n < 4; ++n) bfr[n] = *(const bf16x8*)(pb + n*16*32);
#pragma unroll
    for (int m = 0; m < 4; ++m)
#pragma unroll
      for (int n = 0; n < 4; ++n)
        acc[m][n] = __builtin_amdgcn_mfma_f32_16x16x32_bf16(af[m], bfr[n], acc[m][n], 0, 0, 0);
    __syncthreads();
  }

  const int region = bn >> 4;                 // 0=Q, 1=K, 2=V
  const int bn2 = bn & 15;
  const int cr = bm*128 + wr*64 + (lane >> 4) * 4;   // row base (j=0)
  const int cc = bn2*128 + wc*64 + (lane & 15);      // col within region

  if (region < 2) {
    // Q gets 1/sqrt(128)*log2(e) folded in (softmax uses exp2)
    const float scale = (region == 0) ? (0.08838834764831845f * 1.4426950408889634f) : 1.0f;
    ushort* C = (region == 0) ? Qo : Ko;
#pragma unroll
    for (int m = 0; m < 4; ++m)
#pragma unroll
      for (int n = 0; n < 4; ++n)
#pragma unroll
        for (int j = 0; j < 4; ++j)
          C[(long)(cr + m*16 + j) * DD + (cc + n*16)] = f2bf(acc[m][n][j] * scale);
  } else {
    // V transposed: Vt[(b*NH+h)*HDIM + d][s]; the 4 j-rows are 4 contiguous s
#pragma unroll
    for (int m = 0; m < 4; ++m) {
      int sg = cr + m*16;
      int b2 = sg >> 11, s2 = sg & 2047;
#pragma unroll
      for (int n = 0; n < 4; ++n) {
        int colv = cc + n*16;
        int h2 = colv >> 7, d2 = colv & 127;
        u16x4 pk;
        pk[0] = f2bf(acc[m][n][0]); pk[1] = f2bf(acc[m][n][1]);
        pk[2] = f2bf(acc[m][n][2]); pk[3] = f2bf(acc[m][n][3]);
        *(u16x4*)(Vt + ((long)((b2*NH + h2)*HDIM + d2)) * SS + s2) = pk;
      }
    }
  }
}

// ---------------- plain GEMM for the output projection -----------------------
__global__ __launch_bounds__(256) void gemm_bt_f32(
    const ushort* __restrict__ A, const ushort* __restrict__ Bt,
    float* __restrict__ C, int Mm, int Nn)
{
  __shared__ ushort As[4096];
  __shared__ ushort Bs[4096];
  const int nbn = Nn >> 7;
  const int nwg = (Mm >> 7) * nbn;
  int bid = blockIdx.x;
  int swz = (bid & 7) * (nwg >> 3) + (bid >> 3);
  int bm = swz / nbn, bn = swz % nbn;
  const int t = threadIdx.x;
  const int lane = t & 63;
  const int wr = t >> 7, wc = (t >> 6) & 1;

  f32x4 acc[4][4] = {};

  const ushort* ga0 = A  + (long)(bm*128 + (t>>2)) * DD + (t&3)*8;
  const ushort* ga1 = ga0 + (long)64 * DD;
  const ushort* gb0 = Bt + (long)(bn*128 + (t>>2)) * DD + (t&3)*8;
  const ushort* gb1 = gb0 + (long)64 * DD;
  ushort* la0 = As + t*8;  ushort* la1 = As + 2048 + t*8;
  ushort* lb0 = Bs + t*8;  ushort* lb1 = Bs + 2048 + t*8;

  const ushort* pa = As + (wr*64 + (lane & 15)) * 32 + (lane >> 4) * 8;
  const ushort* pb = Bs + (wc*64 + (lane & 15)) * 32 + (lane >> 4) * 8;

  for (int kt = 0; kt < DD; kt += 32) {
    gld_lds16(ga0, la0); gld_lds16(ga1, la1);
    gld_lds16(gb0, lb0); gld_lds16(gb1, lb1);
    ga0 += 32; ga1 += 32; gb0 += 32; gb1 += 32;
    __syncthreads();
    bf16x8 af[4], bfr[4];
#pragma unroll
    for (int m = 0; m < 4; ++m) af[m]  = *(const bf16x8*)(pa + m*16*32);
#pragma unroll
    for (int n = 0; n < 4; ++n) bfr[n] = *(const bf16x8*)(pb + n*16*32);
#pragma unroll
    for (int m = 0; m < 4; ++m)
#pragma unroll
      for (int n = 0; n < 4; ++n)
        acc[m][n] = __builtin_amdgcn_mfma_f32_16x16x32_bf16(af[m], bfr[n], acc[m][n], 0, 0, 0);
    __syncthreads();
  }

  int cr = bm*128 + wr*64 + (lane >> 4) * 4;
  int cc = bn*128 + wc*64 + (lane & 15);
#pragma unroll
  for (int m = 0; m < 4; ++m)
#pragma unroll
    for (int n = 0; n < 4; ++n)
#pragma unroll
      for (int j = 0; j < 4; ++j)
        C[(long)(cr + m*16 + j) * Nn + (cc + n*16)] = acc[m][n][j];
}

// ---------------- causal flash attention (8 waves x 16 q-rows) ---------------
// K staged via global_load_lds with pre-swizzled source (read XOR (r&7)<<4);
// V already transposed in global -> staged the same way; no scalar transpose.
__global__ __launch_bounds__(512, 4) void attn_fwd(
    const ushort* __restrict__ Qb, const ushort* __restrict__ Kb,
    const ushort* __restrict__ Vtg, ushort* __restrict__ Ob)
{
  __shared__ ushort Ks[64*128];     // [k][d] rows 256B, XOR-swizzled chunks
  __shared__ ushort Vs[128*64];     // [d][k] rows 128B, XOR-swizzled chunks
  __shared__ ushort Ps[8*16*72];    // per-wave P [16][64], padded stride 72

  const int bid = blockIdx.x;
  const int qt = 15 - (bid >> 5);   // LPT: heaviest q-tiles first
  const int bh = bid & 31;
  const int b = bh >> 4, h = bh & 15;
  const int t = threadIdx.x;
  const int lane = t & 63;
  const int wq = t >> 6;            // 0..7
  const int lr = lane & 15, lg = lane >> 4;

  const int qbase = qt * 128;
  const long rowQ = (long)(b * SS + qbase + wq * 16);

  bf16x8 qf[4];                     // Q rows of this wave, pre-scaled
#pragma unroll
  for (int c = 0; c < 4; ++c)
    qf[c] = *(const bf16x8*)(Qb + (rowQ + lr) * DD + h*HDIM + c*32 + lg*8);

  f32x4 accO[8] = {};
  float mrow[4], lrow[4];
#pragma unroll
  for (int j = 0; j < 4; ++j) { mrow[j] = -1e30f; lrow[j] = 0.f; }

  // K staging: 1024 16B-chunks; thread t owns chunks t and 512+t
  const ushort* Kgb = Kb + (long)(b * SS) * DD + h * HDIM;
  const int kr0 = t >> 4, kr1 = 32 + (t >> 4), kci = t & 15;
  const ushort* gk0 = Kgb + (long)kr0 * DD + (kci ^ (kr0 & 7)) * 8;
  const ushort* gk1 = Kgb + (long)kr1 * DD + (kci ^ (kr1 & 7)) * 8;
  ushort* lk0 = Ks + t*8;
  ushort* lk1 = Ks + 4096 + t*8;

  // V^T staging: rows d (128B), 8 chunks each
  const ushort* Vgb = Vtg + (long)(bh * HDIM) * SS;
  const int vd0 = t >> 3, vd1 = 64 + (t >> 3), vci = t & 7;
  const ushort* gv0 = Vgb + (long)vd0 * SS + (vci ^ (vd0 & 7)) * 8;
  const ushort* gv1 = Vgb + (long)vd1 * SS + (vci ^ (vd1 & 7)) * 8;
  ushort* lv0 = Vs + t*8;
  ushort* lv1 = Vs + 4096 + t*8;

  const int ktmax = 2*qt + 1;
  const int qminw = qbase + wq*16;        // wave's FIRST q-row (mask trigger)
  const int qmaxw = qminw + 15;           // wave's last q-row (skip test)
  ushort* myP = Ps + wq * (16*72);

  for (int kt = 0; kt <= ktmax; ++kt) {
    const int k0 = kt * 64;
    gld_lds16(gk0, lk0); gld_lds16(gk1, lk1);
    gld_lds16(gv0, lv0); gld_lds16(gv1, lv1);
    gk0 += (long)64 * DD; gk1 += (long)64 * DD;
    gv0 += 64; gv1 += 64;
    __syncthreads();                 // drains vmcnt -> LDS tiles ready

    if (k0 <= qmaxw) {
      f32x4 sc[4] = {};
#pragma unroll
      for (int n = 0; n < 4; ++n) {  // S = Q K^T (this wave's 16 q-rows)
        int r = n*16 + lr;
        int swz = (r & 7) << 4;
#pragma unroll
        for (int c = 0; c < 4; ++c) {
          bf16x8 kf = *(const bf16x8*)((const char*)Ks + ((r*256 + c*64 + lg*16) ^ swz));
          sc[n] = __builtin_amdgcn_mfma_f32_16x16x32_bf16(qf[c], kf, sc[n], 0,0,0);
        }
      }
      if (k0 + 63 > qminw) {         // tile has keys beyond wave's FIRST row
#pragma unroll
        for (int n = 0; n < 4; ++n)
#pragma unroll
          for (int j = 0; j < 4; ++j) {
            int kpos = k0 + n*16 + lr;
            int qpos = qminw + lg*4 + j;
            if (kpos > qpos) sc[n][j] = -1e30f;
          }
      }
      float al[4];
#pragma unroll
      for (int j = 0; j < 4; ++j) {  // online softmax in log2 domain
        float tm = fmaxf(fmaxf(sc[0][j], sc[1][j]), fmaxf(sc[2][j], sc[3][j]));
#pragma unroll
        for (int off = 1; off < 16; off <<= 1) tm = fmaxf(tm, __shfl_xor(tm, off));
        float mn = fmaxf(mrow[j], tm);
        float a = fast_exp2(mrow[j] - mn);
        mrow[j] = mn;
        float ts = 0.f;
#pragma unroll
        for (int n = 0; n < 4; ++n) {
          float p = fast_exp2(sc[n][j] - mn);
          sc[n][j] = p; ts += p;
        }
#pragma unroll
        for (int off = 1; off < 16; off <<= 1) ts += __shfl_xor(ts, off);
        lrow[j] = lrow[j] * a + ts;
        al[j] = a;
      }
#pragma unroll
      for (int dg = 0; dg < 8; ++dg) {
        f32x4 v = accO[dg];
        v[0] *= al[0]; v[1] *= al[1]; v[2] *= al[2]; v[3] *= al[3];
        accO[dg] = v;
      }
#pragma unroll
      for (int n = 0; n < 4; ++n)    // P -> per-wave LDS (D-layout -> A-layout)
#pragma unroll
        for (int j = 0; j < 4; ++j)
          myP[(lg*4 + j)*72 + n*16 + lr] = f2bf(sc[n][j]);
      bf16x8 pa0 = *(const bf16x8*)(myP + lr*72 + lg*8);
      bf16x8 pa1 = *(const bf16x8*)(myP + lr*72 + 32 + lg*8);
#pragma unroll
      for (int dg = 0; dg < 8; ++dg) {   // O += P V
        int d = dg*16 + lr;
        int vswz = (d & 7) << 4;
        bf16x8 v0 = *(const bf16x8*)((const char*)Vs + ((d*128 + lg*16) ^ vswz));
        bf16x8 v1 = *(const bf16x8*)((const char*)Vs + ((d*128 + 64 + lg*16) ^ vswz));
        accO[dg] = __builtin_amdgcn_mfma_f32_16x16x32_bf16(pa0, v0, accO[dg], 0,0,0);
        accO[dg] = __builtin_amdgcn_mfma_f32_16x16x32_bf16(pa1, v1, accO[dg], 0,0,0);
      }
    }
    __syncthreads();                 // reads done before restage
  }

  float inv[4];
#pragma unroll
  for (int j = 0; j < 4; ++j) inv[j] = 1.0f / lrow[j];
  ushort* Og = Ob + rowQ * DD + h * HDIM;
#pragma unroll
  for (int dg = 0; dg < 8; ++dg)
#pragma unroll
    for (int j = 0; j < 4; ++j)
      Og[(long)(lg*4 + j) * DD + dg*16 + lr] = f2bf(accO[dg][j] * inv[j]);
}

// ---------------- launch ----------------------------------------------------
extern "C" void kernel_launch(void* const* d_in, const int* in_sizes, int n_in,
                              void* d_out, int out_size, void* d_ws, size_t ws_size,
                              hipStream_t stream) {
  const float* x  = (const float*)d_in[0];
  const float* Wq = (const float*)d_in[1];
  const float* Wk = (const float*)d_in[2];
  const float* Wv = (const float*)d_in[3];
  const float* Wo = (const float*)d_in[4];

  ushort* ws  = (ushort*)d_ws;
  ushort* xb  = ws;                         // x bf16; later reused as attn-out
  ushort* wqb = ws  + (long)MM*DD;          // wq/wk/wv contiguous = fused Bt
  ushort* wkb = wqb + (long)DD*DD;
  ushort* wvb = wkb + (long)DD*DD;
  ushort* wob = wvb + (long)DD*DD;
  ushort* Qb  = wob + (long)DD*DD;
  ushort* Kb  = Qb  + (long)MM*DD;
  ushort* Vtg = Kb  + (long)MM*DD;          // V stored transposed [bh*128+d][s]
  (void)wkb; (void)wvb;

  const int CVT_BLOCKS = (MM*DD + 4*DD*DD) / 8 / 256;   // 12288
  cvt_all<<<CVT_BLOCKS, 256, 0, stream>>>(x, Wq, Wk, Wv, Wo, ws);

  gemm_qkv<<<1536, 256, 0, stream>>>(xb, wqb, Qb, Kb, Vtg);

  attn_fwd<<<512, 512, 0, stream>>>(Qb, Kb, Vtg, xb);   // attn out -> xb

  gemm_bt_f32<<<512, 256, 0, stream>>>(xb, wob, (float*)d_out, MM, DD);
}

// Round 5
// 278.434 us; speedup vs baseline: 1.3082x; 1.1491x over previous
//
#include <hip/hip_runtime.h>
#include <stdint.h>

#define DD 2048
#define SS 2048
#define NB 2
#define NH 16
#define HDIM 128
#define MM (NB*SS)   // 4096 rows

typedef __attribute__((ext_vector_type(8))) short bf16x8;
typedef __attribute__((ext_vector_type(4))) float f32x4;
typedef __attribute__((ext_vector_type(4))) ushort u16x4;

__device__ __forceinline__ float fast_exp2(float x) {
  return __builtin_amdgcn_exp2f(x);   // v_exp_f32 (2^x natively)
}

__device__ __forceinline__ ushort f2bf(float f) {
  union { float f; uint32_t u; } v; v.f = f;
  uint32_t u = v.u;
  return (ushort)((u + 0x7fffu + ((u >> 16) & 1u)) >> 16);
}

__device__ __forceinline__ void gld_lds16(const ushort* g, ushort* l) {
  __builtin_amdgcn_global_load_lds(
      (const __attribute__((address_space(1))) void*)g,
      (__attribute__((address_space(3))) void*)l, 16, 0, 0);
}

// ---------------- fp32 -> bf16 conversion of x and the 4 weights -------------
__global__ __launch_bounds__(256) void cvt_all(
    const float* __restrict__ x, const float* __restrict__ wq,
    const float* __restrict__ wk, const float* __restrict__ wv,
    const float* __restrict__ wo, ushort* __restrict__ dst)
{
  int i8 = blockIdx.x * 256 + threadIdx.x;   // one 8-float chunk per thread
  const int X8 = MM * DD / 8;                // 1,048,576
  const int W8 = DD * DD / 8;                // 524,288
  const float* src; int off;
  if (i8 < X8)            { src = x;  off = i8; }
  else if (i8 < X8 +   W8){ src = wq; off = i8 - X8; }
  else if (i8 < X8 + 2*W8){ src = wk; off = i8 - (X8 +   W8); }
  else if (i8 < X8 + 3*W8){ src = wv; off = i8 - (X8 + 2*W8); }
  else                    { src = wo; off = i8 - (X8 + 3*W8); }
  const float4* p = (const float4*)src;
  float4 a = p[(long)off*2], b = p[(long)off*2 + 1];
  bf16x8 o;
  o[0]=(short)f2bf(a.x); o[1]=(short)f2bf(a.y); o[2]=(short)f2bf(a.z); o[3]=(short)f2bf(a.w);
  o[4]=(short)f2bf(b.x); o[5]=(short)f2bf(b.y); o[6]=(short)f2bf(b.z); o[7]=(short)f2bf(b.w);
  *(bf16x8*)(dst + (long)i8*8) = o;
}

// ------------- pipelined GEMM: 256x128 tile, BK=64, 8 waves, dbuf+vmcnt ------
// MODE 0: QKV fused (N=6144): Q (scaled bf16), K (bf16), V transposed.
// MODE 1: O-proj (N=2048): f32 out.
// LDS per buffer: A 256x64 (32KB) + B 128x64 (16KB); 2 buffers = 96 KB.
// Counted-vmcnt pipeline: stage kt+2 after read-barrier, wait vmcnt(6).
template<int MODE>
__global__ __launch_bounds__(512, 2) void gemm_pipe(
    const ushort* __restrict__ A, const ushort* __restrict__ Bt,
    ushort* __restrict__ Qo, ushort* __restrict__ Ko, ushort* __restrict__ Vt,
    float* __restrict__ Cf)
{
  __shared__ ushort lds[2 * 24576];          // 96 KB
  const int NBX = (MODE == 0) ? 6 : 2;       // bn per XCD chunk
  const int t = threadIdx.x;
  const int bid = blockIdx.x;
  const int xcd = bid & 7, local = bid >> 3;
  const int bm = local / NBX;
  const int bn = xcd * NBX + (local - bm * NBX);
  const int lane = t & 63;
  const int w = t >> 6;
  const int wr = w >> 1, wcn = w & 1;        // 4M x 2N wave grid
  const int lr = lane & 15, lg = lane >> 4;

  // staging descriptors: A = 4 chunks/thread, B = 2 chunks/thread (16B each)
  // chunk c: row=c>>3, slot=c&7, global k-chunk = slot ^ (row&7)  (T2 swizzle)
  int aoff[4], aldo[4], boff[2], bldo[2];
#pragma unroll
  for (int i = 0; i < 4; ++i) {
    int c = i*512 + t, row = c >> 3, slot = c & 7, gc = slot ^ (row & 7);
    aoff[i] = row*DD + gc*8; aldo[i] = c*8;
  }
#pragma unroll
  for (int i = 0; i < 2; ++i) {
    int c = i*512 + t, row = c >> 3, slot = c & 7, gc = slot ^ (row & 7);
    boff[i] = row*DD + gc*8; bldo[i] = 16384 + c*8;  // B at ushort 256*64
  }
  const ushort* Abase = A  + (long)(bm*256) * DD;
  const ushort* Bbase = Bt + (long)(bn*128) * DD;

#define STAGE(KT, BUF) do {                                   \
    const ushort* a_ = Abase + (KT)*64;                       \
    const ushort* b_ = Bbase + (KT)*64;                       \
    ushort* l_ = lds + (BUF)*24576;                           \
    gld_lds16(a_ + aoff[0], l_ + aldo[0]);                    \
    gld_lds16(a_ + aoff[1], l_ + aldo[1]);                    \
    gld_lds16(a_ + aoff[2], l_ + aldo[2]);                    \
    gld_lds16(a_ + aoff[3], l_ + aldo[3]);                    \
    gld_lds16(b_ + boff[0], l_ + bldo[0]);                    \
    gld_lds16(b_ + boff[1], l_ + bldo[1]);                    \
  } while (0)

  f32x4 acc[4][4] = {};
  const int T = DD / 64;                     // 32 K-tiles

  STAGE(0, 0);
  STAGE(1, 1);
  asm volatile("s_waitcnt vmcnt(6)" ::: "memory");   // tile0 landed
  __builtin_amdgcn_sched_barrier(0);
  __builtin_amdgcn_s_barrier();
  __builtin_amdgcn_sched_barrier(0);

  for (int kt = 0; kt < T; ++kt) {
    const char* lb = (const char*)lds + (kt & 1) * 49152;
#pragma unroll
    for (int ks = 0; ks < 2; ++ks) {
      bf16x8 af[4], bfr[4];
#pragma unroll
      for (int m = 0; m < 4; ++m) {
        int row = wr*64 + m*16 + lr;
        af[m] = *(const bf16x8*)(lb + row*128 + (((ks*4 + lg) ^ (row & 7)) * 16));
      }
#pragma unroll
      for (int n = 0; n < 4; ++n) {
        int row = wcn*64 + n*16 + lr;
        bfr[n] = *(const bf16x8*)(lb + 32768 + row*128 + (((ks*4 + lg) ^ (row & 7)) * 16));
      }
      __builtin_amdgcn_s_setprio(1);
#pragma unroll
      for (int m = 0; m < 4; ++m)
#pragma unroll
        for (int n = 0; n < 4; ++n)
          acc[m][n] = __builtin_amdgcn_mfma_f32_16x16x32_bf16(af[m], bfr[n], acc[m][n], 0, 0, 0);
      __builtin_amdgcn_s_setprio(0);
    }
    __builtin_amdgcn_sched_barrier(0);
    __builtin_amdgcn_s_barrier();            // all waves done reading buf[cur]
    __builtin_amdgcn_sched_barrier(0);
    if (kt + 2 < T) {
      STAGE(kt + 2, kt & 1);                 // overwrite just-freed buffer
      asm volatile("s_waitcnt vmcnt(6)" ::: "memory");  // tile kt+1 landed
    } else if (kt + 1 < T) {
      asm volatile("s_waitcnt vmcnt(0)" ::: "memory");  // pipeline drain (tail)
    }
    __builtin_amdgcn_sched_barrier(0);
    __builtin_amdgcn_s_barrier();            // all threads observed tile kt+1
    __builtin_amdgcn_sched_barrier(0);
  }
#undef STAGE

  // epilogue: C/D layout col=lane&15, row=(lane>>4)*4+j
  if (MODE == 0) {
    const int region = bn >> 4;              // 0=Q, 1=K, 2=V
    const int bn2 = bn & 15;
    const int ccb = bn2*128 + wcn*64 + lr;
    const int crb = bm*256 + wr*64 + lg*4;
    if (region < 2) {
      const float scale = (region == 0) ? (0.08838834764831845f * 1.4426950408889634f) : 1.0f;
      ushort* C = (region == 0) ? Qo : Ko;
#pragma unroll
      for (int m = 0; m < 4; ++m)
#pragma unroll
        for (int n = 0; n < 4; ++n)
#pragma unroll
          for (int j = 0; j < 4; ++j)
            C[(long)(crb + m*16 + j) * DD + (ccb + n*16)] = f2bf(acc[m][n][j] * scale);
    } else {
      // V transposed: Vt[(b*NH+h)*HDIM + d][s]; 4 j-rows = 4 contiguous s
#pragma unroll
      for (int m = 0; m < 4; ++m) {
        int sg = crb + m*16;
        int b2 = sg >> 11, s2 = sg & 2047;
#pragma unroll
        for (int n = 0; n < 4; ++n) {
          int colv = ccb + n*16;
          int h2 = colv >> 7, d2 = colv & 127;
          u16x4 pk;
          pk[0] = f2bf(acc[m][n][0]); pk[1] = f2bf(acc[m][n][1]);
          pk[2] = f2bf(acc[m][n][2]); pk[3] = f2bf(acc[m][n][3]);
          *(u16x4*)(Vt + ((long)((b2*NH + h2)*HDIM + d2)) * SS + s2) = pk;
        }
      }
    }
  } else {
    const int ccb = bn*128 + wcn*64 + lr;
    const int crb = bm*256 + wr*64 + lg*4;
#pragma unroll
    for (int m = 0; m < 4; ++m)
#pragma unroll
      for (int n = 0; n < 4; ++n)
#pragma unroll
        for (int j = 0; j < 4; ++j)
          Cf[(long)(crb + m*16 + j) * DD + (ccb + n*16)] = acc[m][n][j];
  }
}

// ---------------- causal flash attention (8 waves x 16 q-rows) ---------------
// K staged via global_load_lds with pre-swizzled source (read XOR (r&7)<<4);
// V already transposed in global -> staged the same way; no scalar transpose.
__global__ __launch_bounds__(512, 4) void attn_fwd(
    const ushort* __restrict__ Qb, const ushort* __restrict__ Kb,
    const ushort* __restrict__ Vtg, ushort* __restrict__ Ob)
{
  __shared__ ushort Ks[64*128];     // [k][d] rows 256B, XOR-swizzled chunks
  __shared__ ushort Vs[128*64];     // [d][k] rows 128B, XOR-swizzled chunks
  __shared__ ushort Ps[8*16*72];    // per-wave P [16][64], padded stride 72

  const int bid = blockIdx.x;
  const int qt = 15 - (bid >> 5);   // LPT: heaviest q-tiles first
  const int bh = bid & 31;
  const int b = bh >> 4, h = bh & 15;
  const int t = threadIdx.x;
  const int lane = t & 63;
  const int wq = t >> 6;            // 0..7
  const int lr = lane & 15, lg = lane >> 4;

  const int qbase = qt * 128;
  const long rowQ = (long)(b * SS + qbase + wq * 16);

  bf16x8 qf[4];                     // Q rows of this wave, pre-scaled
#pragma unroll
  for (int c = 0; c < 4; ++c)
    qf[c] = *(const bf16x8*)(Qb + (rowQ + lr) * DD + h*HDIM + c*32 + lg*8);

  f32x4 accO[8] = {};
  float mrow[4], lrow[4];
#pragma unroll
  for (int j = 0; j < 4; ++j) { mrow[j] = -1e30f; lrow[j] = 0.f; }

  // K staging: 1024 16B-chunks; thread t owns chunks t and 512+t
  const ushort* Kgb = Kb + (long)(b * SS) * DD + h * HDIM;
  const int kr0 = t >> 4, kr1 = 32 + (t >> 4), kci = t & 15;
  const ushort* gk0 = Kgb + (long)kr0 * DD + (kci ^ (kr0 & 7)) * 8;
  const ushort* gk1 = Kgb + (long)kr1 * DD + (kci ^ (kr1 & 7)) * 8;
  ushort* lk0 = Ks + t*8;
  ushort* lk1 = Ks + 4096 + t*8;

  // V^T staging: rows d (128B), 8 chunks each
  const ushort* Vgb = Vtg + (long)(bh * HDIM) * SS;
  const int vd0 = t >> 3, vd1 = 64 + (t >> 3), vci = t & 7;
  const ushort* gv0 = Vgb + (long)vd0 * SS + (vci ^ (vd0 & 7)) * 8;
  const ushort* gv1 = Vgb + (long)vd1 * SS + (vci ^ (vd1 & 7)) * 8;
  ushort* lv0 = Vs + t*8;
  ushort* lv1 = Vs + 4096 + t*8;

  const int ktmax = 2*qt + 1;
  const int qminw = qbase + wq*16;        // wave's FIRST q-row (mask trigger)
  const int qmaxw = qminw + 15;           // wave's last q-row (skip test)
  ushort* myP = Ps + wq * (16*72);

  for (int kt = 0; kt <= ktmax; ++kt) {
    const int k0 = kt * 64;
    gld_lds16(gk0, lk0); gld_lds16(gk1, lk1);
    gld_lds16(gv0, lv0); gld_lds16(gv1, lv1);
    gk0 += (long)64 * DD; gk1 += (long)64 * DD;
    gv0 += 64; gv1 += 64;
    __syncthreads();                 // drains vmcnt -> LDS tiles ready

    if (k0 <= qmaxw) {
      f32x4 sc[4] = {};
#pragma unroll
      for (int n = 0; n < 4; ++n) {  // S = Q K^T (this wave's 16 q-rows)
        int r = n*16 + lr;
        int swz = (r & 7) << 4;
#pragma unroll
        for (int c = 0; c < 4; ++c) {
          bf16x8 kf = *(const bf16x8*)((const char*)Ks + ((r*256 + c*64 + lg*16) ^ swz));
          sc[n] = __builtin_amdgcn_mfma_f32_16x16x32_bf16(qf[c], kf, sc[n], 0,0,0);
        }
      }
      if (k0 + 63 > qminw) {         // tile has keys beyond wave's FIRST row
#pragma unroll
        for (int n = 0; n < 4; ++n)
#pragma unroll
          for (int j = 0; j < 4; ++j) {
            int kpos = k0 + n*16 + lr;
            int qpos = qminw + lg*4 + j;
            if (kpos > qpos) sc[n][j] = -1e30f;
          }
      }
      float al[4];
#pragma unroll
      for (int j = 0; j < 4; ++j) {  // online softmax in log2 domain
        float tm = fmaxf(fmaxf(sc[0][j], sc[1][j]), fmaxf(sc[2][j], sc[3][j]));
#pragma unroll
        for (int off = 1; off < 16; off <<= 1) tm = fmaxf(tm, __shfl_xor(tm, off));
        float mn = fmaxf(mrow[j], tm);
        float a = fast_exp2(mrow[j] - mn);
        mrow[j] = mn;
        float ts = 0.f;
#pragma unroll
        for (int n = 0; n < 4; ++n) {
          float p = fast_exp2(sc[n][j] - mn);
          sc[n][j] = p; ts += p;
        }
#pragma unroll
        for (int off = 1; off < 16; off <<= 1) ts += __shfl_xor(ts, off);
        lrow[j] = lrow[j] * a + ts;
        al[j] = a;
      }
#pragma unroll
      for (int dg = 0; dg < 8; ++dg) {
        f32x4 v = accO[dg];
        v[0] *= al[0]; v[1] *= al[1]; v[2] *= al[2]; v[3] *= al[3];
        accO[dg] = v;
      }
#pragma unroll
      for (int n = 0; n < 4; ++n)    // P -> per-wave LDS (D-layout -> A-layout)
#pragma unroll
        for (int j = 0; j < 4; ++j)
          myP[(lg*4 + j)*72 + n*16 + lr] = f2bf(sc[n][j]);
      bf16x8 pa0 = *(const bf16x8*)(myP + lr*72 + lg*8);
      bf16x8 pa1 = *(const bf16x8*)(myP + lr*72 + 32 + lg*8);
#pragma unroll
      for (int dg = 0; dg < 8; ++dg) {   // O += P V
        int d = dg*16 + lr;
        int vswz = (d & 7) << 4;
        bf16x8 v0 = *(const bf16x8*)((const char*)Vs + ((d*128 + lg*16) ^ vswz));
        bf16x8 v1 = *(const bf16x8*)((const char*)Vs + ((d*128 + 64 + lg*16) ^ vswz));
        accO[dg] = __builtin_amdgcn_mfma_f32_16x16x32_bf16(pa0, v0, accO[dg], 0,0,0);
        accO[dg] = __builtin_amdgcn_mfma_f32_16x16x32_bf16(pa1, v1, accO[dg], 0,0,0);
      }
    }
    __syncthreads();                 // reads done before restage
  }

  float inv[4];
#pragma unroll
  for (int j = 0; j < 4; ++j) inv[j] = 1.0f / lrow[j];
  ushort* Og = Ob + rowQ * DD + h * HDIM;
#pragma unroll
  for (int dg = 0; dg < 8; ++dg)
#pragma unroll
    for (int j = 0; j < 4; ++j)
      Og[(long)(lg*4 + j) * DD + dg*16 + lr] = f2bf(accO[dg][j] * inv[j]);
}

// ---------------- launch ----------------------------------------------------
extern "C" void kernel_launch(void* const* d_in, const int* in_sizes, int n_in,
                              void* d_out, int out_size, void* d_ws, size_t ws_size,
                              hipStream_t stream) {
  const float* x  = (const float*)d_in[0];
  const float* Wq = (const float*)d_in[1];
  const float* Wk = (const float*)d_in[2];
  const float* Wv = (const float*)d_in[3];
  const float* Wo = (const float*)d_in[4];

  ushort* ws  = (ushort*)d_ws;
  ushort* xb  = ws;                         // x bf16; later reused as attn-out
  ushort* wqb = ws  + (long)MM*DD;          // wq/wk/wv contiguous = fused Bt
  ushort* wkb = wqb + (long)DD*DD;
  ushort* wvb = wkb + (long)DD*DD;
  ushort* wob = wvb + (long)DD*DD;
  ushort* Qb  = wob + (long)DD*DD;
  ushort* Kb  = Qb  + (long)MM*DD;
  ushort* Vtg = Kb  + (long)MM*DD;          // V stored transposed [bh*128+d][s]
  (void)wkb; (void)wvb;

  const int CVT_BLOCKS = (MM*DD + 4*DD*DD) / 8 / 256;   // 12288
  cvt_all<<<CVT_BLOCKS, 256, 0, stream>>>(x, Wq, Wk, Wv, Wo, ws);

  gemm_pipe<0><<<768, 512, 0, stream>>>(xb, wqb, Qb, Kb, Vtg, nullptr);

  attn_fwd<<<512, 512, 0, stream>>>(Qb, Kb, Vtg, xb);   // attn out -> xb

  gemm_pipe<1><<<256, 512, 0, stream>>>(xb, wob, nullptr, nullptr, nullptr,
                                        (float*)d_out);
}